// Round 1
// baseline (160.595 us; speedup 1.0000x reference)
//
#include <hip/hip_runtime.h>

// ---------------------------------------------------------------------------
// DCT-conv:  out = IDCT_H( circconv_W( DCT_H(x), DCT_H(pad(w)) ) summed over ci ) + bias
// B=8, c_in=64, c_out=128, H=W=128, kh=kw=5.
//
// Pipeline (all fp16 storage, fp32 MFMA accumulate):
//   k_dm   : D[k][h], M[h][k] DCT matrices (fp16)
//   k_wd   : WD blocked [k][s=10][co=128][kk=32], s=(j= s>>1, ci-half = s&1)
//   k_dctH : xd[k][b][ci][w] = D @ x[b][ci]          (512 wgs, 128^3 GEMM each)
//   k_conv : y2[b][k][co][w] = sum_{j,ci} WD * xd shifted   (1024 wgs)
//   k_idct : out[b][co][h][w] = M @ y2 + bias        (1024 wgs, fp32 out)
// ---------------------------------------------------------------------------

using half8v = __attribute__((ext_vector_type(8))) _Float16;
using half4v = __attribute__((ext_vector_type(4))) _Float16;
using f32x4  = __attribute__((ext_vector_type(4))) float;

#define PI_F 3.14159265358979323846f

// XOR-swizzled LDS offset for [n][K] layouts (16B chunks of 8 fp16).
// chunk c stored at (c ^ (n & mask)) -> b128 frag reads stay 16B-aligned, ~2-way conflicts.
__device__ __forceinline__ int sw_off(int n, int k, int K, int mask) {
    int c = k >> 3;
    return n * K + (((c ^ (n & mask)) << 3) | (k & 7));
}

// ---------------------------------------------------------------------------
__global__ void k_dm(_Float16* __restrict__ D, _Float16* __restrict__ M) {
    int k = blockIdx.x;     // 0..127
    int h = threadIdx.x;    // 0..127
    float ang = PI_F * (float)((2 * h + 1) * k) * (1.0f / 256.0f);
    float c = cosf(ang);
    D[k * 128 + h] = (_Float16)(2.0f * c);
    float wk = (k == 0) ? 0.5f : 1.0f;
    M[h * 128 + k] = (_Float16)(c * wk * (1.0f / 256.0f));
}

// WD[((k*10+s)*128+co)*32+kk] = sum_i 2cos(pi(2i+1)k/256) * w[co][ci][i][j]
//   with j = s>>1, ci = (s&1)*32 + kk
__global__ void k_wd(const float* __restrict__ w, _Float16* __restrict__ WD) {
    int bid = blockIdx.x;           // 0..1279
    int kf = bid / 10, s = bid % 10;
    int j = s >> 1, ci0 = (s & 1) << 5;
    float dv[5];
#pragma unroll
    for (int i = 0; i < 5; ++i)
        dv[i] = 2.0f * cosf(PI_F * (float)((2 * i + 1) * kf) * (1.0f / 256.0f));
    for (int e = threadIdx.x; e < 4096; e += 256) {
        int co = e >> 5, t = e & 31, ci = ci0 + t;
        const float* wp = w + (co * 64 + ci) * 25 + j;
        float acc = 0.f;
#pragma unroll
        for (int i = 0; i < 5; ++i) acc += dv[i] * wp[i * 5];
        WD[bid * 4096 + e] = (_Float16)acc;
    }
}

// ---------------------------------------------------------------------------
// Shared 128x128x128 GEMM core: lA = [m][K=128] swizzled, lB = [n][K=128] swizzled.
__device__ __forceinline__ void gemm128(const _Float16* lA, const _Float16* lB,
                                        f32x4 acc[4][4], int tid) {
    int lane = tid & 63, ln = lane & 15, q = lane >> 4;
    int wave = tid >> 6, wm = wave >> 1, wn = wave & 1;
#pragma unroll
    for (int s = 0; s < 4; ++s) {
        half8v af[4], bf[4];
#pragma unroll
        for (int mt = 0; mt < 4; ++mt) {
            int m = wm * 64 + mt * 16 + ln;
            af[mt] = *(const half8v*)(&lA[m * 128 + (((s * 4 + q) ^ (m & 15)) << 3)]);
        }
#pragma unroll
        for (int nt = 0; nt < 4; ++nt) {
            int n = wn * 64 + nt * 16 + ln;
            bf[nt] = *(const half8v*)(&lB[n * 128 + (((s * 4 + q) ^ (n & 15)) << 3)]);
        }
#pragma unroll
        for (int mt = 0; mt < 4; ++mt)
#pragma unroll
            for (int nt = 0; nt < 4; ++nt)
                acc[mt][nt] = __builtin_amdgcn_mfma_f32_16x16x32_f16(af[mt], bf[nt], acc[mt][nt], 0, 0, 0);
    }
}

// Copy a plain [128][128] fp16 matrix (rows = m, K contiguous) into swizzled LDS.
__device__ __forceinline__ void stage_copyA(const _Float16* __restrict__ g, _Float16* l, int tid) {
    const half8v* gs = (const half8v*)g;
#pragma unroll
    for (int r = 0; r < 8; ++r) {
        int gg = tid + r * 256;
        int m = gg >> 4, c = gg & 15;
        *(half8v*)(&l[m * 128 + (((c ^ (m & 15)) << 3))]) = gs[gg];
    }
}

// Transpose-stage fp16 source rows [k][128 w] (row k at src + k*row_stride) into
// swizzled LDS [n=w][K], K in {64,128}.
__device__ __forceinline__ void stage_transB(const _Float16* __restrict__ src, int row_stride,
                                             _Float16* l, int K, int mask, int nblocks, int tid) {
    for (int blk = tid; blk < nblocks; blk += 256) {
        int kb = blk >> 4, wb = blk & 15;
        int k0 = kb * 4, w0 = wb * 8;
        half8v r0 = *(const half8v*)(&src[(k0 + 0) * row_stride + w0]);
        half8v r1 = *(const half8v*)(&src[(k0 + 1) * row_stride + w0]);
        half8v r2 = *(const half8v*)(&src[(k0 + 2) * row_stride + w0]);
        half8v r3 = *(const half8v*)(&src[(k0 + 3) * row_stride + w0]);
#pragma unroll
        for (int dw = 0; dw < 8; ++dw) {
            int n = w0 + dw;
            half4v p = {r0[dw], r1[dw], r2[dw], r3[dw]};
            *(half4v*)(&l[sw_off(n, k0, K, mask)]) = p;
        }
    }
}

// ---------------------------------------------------------------------------
// Step A: xd[k][b][ci][w] = sum_h D[k][h] * x[b][ci][h][w]
__global__ __launch_bounds__(256) void k_dctH(const float* __restrict__ x,
                                              const _Float16* __restrict__ Dg,
                                              _Float16* __restrict__ xd) {
    __shared__ _Float16 lA[128 * 128];
    __shared__ _Float16 lB[128 * 128];
    int b = blockIdx.x >> 6, ci = blockIdx.x & 63;
    int tid = threadIdx.x;

    stage_copyA(Dg, lA, tid);

    const float* xs = x + (long)(b * 64 + ci) * 16384;
#pragma unroll
    for (int rep = 0; rep < 2; ++rep) {
        int blk = tid + rep * 256;
        int hb = blk >> 4, wb = blk & 15;
        int h0 = hb * 4, w0 = wb * 8;
        f32x4 f[4][2];
#pragma unroll
        for (int dh = 0; dh < 4; ++dh) {
            f[dh][0] = *(const f32x4*)(&xs[(h0 + dh) * 128 + w0]);
            f[dh][1] = *(const f32x4*)(&xs[(h0 + dh) * 128 + w0 + 4]);
        }
#pragma unroll
        for (int dw = 0; dw < 8; ++dw) {
            int n = w0 + dw;
            half4v p = {(_Float16)f[0][dw >> 2][dw & 3], (_Float16)f[1][dw >> 2][dw & 3],
                        (_Float16)f[2][dw >> 2][dw & 3], (_Float16)f[3][dw >> 2][dw & 3]};
            *(half4v*)(&lB[sw_off(n, h0, 128, 15)]) = p;
        }
    }
    __syncthreads();

    f32x4 acc[4][4] = {};
    gemm128(lA, lB, acc, tid);

    int lane = tid & 63, ln = lane & 15, q = lane >> 4;
    int wave = tid >> 6, wm = wave >> 1, wn = wave & 1;
#pragma unroll
    for (int mt = 0; mt < 4; ++mt)
#pragma unroll
        for (int nt = 0; nt < 4; ++nt)
#pragma unroll
            for (int r = 0; r < 4; ++r) {
                int kk = wm * 64 + mt * 16 + q * 4 + r;
                int wcol = wn * 64 + nt * 16 + ln;
                xd[((long)(kk * 8 + b) * 64 + ci) * 128 + wcol] = (_Float16)acc[mt][nt][r];
            }
}

// ---------------------------------------------------------------------------
// Step B: per (k,b):  y2[b][k][co][w] = sum_{s=0..9} sum_{kk} WD[k][s][co][kk] * xd[k][b][ci][(w-j)&127]
__global__ __launch_bounds__(256) void k_conv(const _Float16* __restrict__ xd,
                                              const _Float16* __restrict__ WD,
                                              _Float16* __restrict__ y2) {
    __shared__ _Float16 lX[128 * 64];        // [w][ci] swizzled, mask=7
    __shared__ _Float16 lW[2][128 * 40];     // [co][kk] padded rows of 40
    int k = blockIdx.x >> 3, b = blockIdx.x & 7;
    int tid = threadIdx.x;

    // stage xd^T  (64 rows of 128)
    const _Float16* xs = xd + (long)(k * 8 + b) * 8192;
    stage_transB(xs, 128, lX, 64, 7, 256, tid);

    // stage W tile 0
    {
        const half8v* wt0 = (const half8v*)(WD + (long)(k * 10) * 4096);
#pragma unroll
        for (int p = 0; p < 2; ++p) {
            int g = tid + p * 256;
            int m = g >> 2, c = g & 3;
            *(half8v*)(&lW[0][m * 40 + c * 8]) = wt0[g];
        }
    }
    __syncthreads();

    int lane = tid & 63, ln = lane & 15, q = lane >> 4;
    int wave = tid >> 6, wm = wave >> 1, wn = wave & 1;
    f32x4 acc[4][4] = {};

    for (int s = 0; s < 10; ++s) {
        half8v pf0, pf1;
        if (s < 9) {
            const half8v* wtn = (const half8v*)(WD + (long)(k * 10 + s + 1) * 4096);
            pf0 = wtn[tid];
            pf1 = wtn[tid + 256];
        }
        int j = s >> 1;
        int cb = (s & 1) << 2;   // chunk base within K=64
        const _Float16* lWc = lW[s & 1];
        half8v af[4], bf[4];
#pragma unroll
        for (int mt = 0; mt < 4; ++mt) {
            int m = wm * 64 + mt * 16 + ln;
            af[mt] = *(const half8v*)(&lWc[m * 40 + q * 8]);
        }
#pragma unroll
        for (int nt = 0; nt < 4; ++nt) {
            int wcol = wn * 64 + nt * 16 + ln;
            int n = (wcol - j) & 127;
            bf[nt] = *(const half8v*)(&lX[n * 64 + (((cb + q) ^ (n & 7)) << 3)]);
        }
#pragma unroll
        for (int mt = 0; mt < 4; ++mt)
#pragma unroll
            for (int nt = 0; nt < 4; ++nt)
                acc[mt][nt] = __builtin_amdgcn_mfma_f32_16x16x32_f16(af[mt], bf[nt], acc[mt][nt], 0, 0, 0);

        if (s < 9) {
            _Float16* dst = lW[(s + 1) & 1];
            {
                int g = tid;
                int m = g >> 2, c = g & 3;
                *(half8v*)(&dst[m * 40 + c * 8]) = pf0;
            }
            {
                int g = tid + 256;
                int m = g >> 2, c = g & 3;
                *(half8v*)(&dst[m * 40 + c * 8]) = pf1;
            }
            __syncthreads();
        }
    }

    _Float16* yb = y2 + (long)(b * 128 + k) * 16384;
#pragma unroll
    for (int mt = 0; mt < 4; ++mt)
#pragma unroll
        for (int nt = 0; nt < 4; ++nt)
#pragma unroll
            for (int r = 0; r < 4; ++r) {
                int co = wm * 64 + mt * 16 + q * 4 + r;
                int wcol = wn * 64 + nt * 16 + ln;
                yb[co * 128 + wcol] = (_Float16)acc[mt][nt][r];
            }
}

// ---------------------------------------------------------------------------
// Step C: out[b][co][h][w] = sum_k M[h][k] * y2[b][k][co][w] + bias[co]
__global__ __launch_bounds__(256) void k_idct(const _Float16* __restrict__ y2,
                                              const _Float16* __restrict__ Mg,
                                              const float* __restrict__ bias,
                                              float* __restrict__ out) {
    __shared__ _Float16 lA[128 * 128];
    __shared__ _Float16 lB[128 * 128];
    int b = blockIdx.x >> 7, co = blockIdx.x & 127;
    int tid = threadIdx.x;

    stage_copyA(Mg, lA, tid);
    // rows k of y2 slice: base + k*16384
    const _Float16* src = y2 + (long)b * 2097152 + co * 128;
    stage_transB(src, 16384, lB, 128, 15, 512, tid);
    __syncthreads();

    f32x4 acc[4][4] = {};
    gemm128(lA, lB, acc, tid);

    float bv = bias[co];
    float* ob = out + ((long)(b * 128 + co)) * 16384;
    int lane = tid & 63, ln = lane & 15, q = lane >> 4;
    int wave = tid >> 6, wm = wave >> 1, wn = wave & 1;
#pragma unroll
    for (int mt = 0; mt < 4; ++mt)
#pragma unroll
        for (int nt = 0; nt < 4; ++nt)
#pragma unroll
            for (int r = 0; r < 4; ++r) {
                int h = wm * 64 + mt * 16 + q * 4 + r;
                int wcol = wn * 64 + nt * 16 + ln;
                ob[h * 128 + wcol] = acc[mt][nt][r] + bv;
            }
}

// ---------------------------------------------------------------------------
extern "C" void kernel_launch(void* const* d_in, const int* in_sizes, int n_in,
                              void* d_out, int out_size, void* d_ws, size_t ws_size,
                              hipStream_t stream) {
    const float* x    = (const float*)d_in[0];  // [8][64][128][128]
    const float* w    = (const float*)d_in[1];  // [128][64][5][5]
    const float* bias = (const float*)d_in[2];  // [128]
    float* out = (float*)d_out;                 // [8][128][128][128]

    char* ws = (char*)d_ws;
    _Float16* D  = (_Float16*)(ws);                                  //  32 KB
    _Float16* M  = (_Float16*)(ws + 32768);                          //  32 KB
    _Float16* WD = (_Float16*)(ws + 65536);                          //  10.0 MB
    _Float16* xd = (_Float16*)(ws + 65536 + 10485760);               //  16 MB
    _Float16* y2 = (_Float16*)(ws + 65536 + 10485760 + 16777216);    //  32 MB

    k_dm  <<<dim3(128),  dim3(128), 0, stream>>>(D, M);
    k_wd  <<<dim3(1280), dim3(256), 0, stream>>>(w, WD);
    k_dctH<<<dim3(512),  dim3(256), 0, stream>>>(x, D, xd);
    k_conv<<<dim3(1024), dim3(256), 0, stream>>>(xd, WD, y2);
    k_idct<<<dim3(1024), dim3(256), 0, stream>>>(y2, M, bias, out);
}

// Round 3
// 159.891 us; speedup vs baseline: 1.0044x; 1.0044x over previous
//
#include <hip/hip_runtime.h>

// ---------------------------------------------------------------------------
// DCT-conv:  out = IDCT_H( circconv_W( DCT_H(x), DCT_H(pad(w)) ) summed over ci ) + bias
// B=8, c_in=64, c_out=128, H=W=128, kh=kw=5.
//
// Pipeline (all fp16 storage, fp32 MFMA accumulate):
//   k_dm   : D[k][h], M[h][k] DCT matrices (fp16)
//   k_wd   : WD blocked [k][s=10][co=128][kk=32], s=(j= s>>1, ci-half = s&1)
//   k_dctH : xd[k][b][ci][w] = D @ x[b][ci]          (512 wgs, 128^3 GEMM each)
//   k_conv : y2[b][k][co][w] = sum_{j,ci} WD * xd shifted   (1024 wgs, b-major,
//            WD read directly from global (L2-hot), barrier-free K-loop)
//   k_idct : out[b][co][h][w] = M @ y2 + bias        (1024 wgs, fp32 out)
// ---------------------------------------------------------------------------

using half8v = __attribute__((ext_vector_type(8))) _Float16;
using half4v = __attribute__((ext_vector_type(4))) _Float16;
using f32x4  = __attribute__((ext_vector_type(4))) float;

#define PI_F 3.14159265358979323846f

// XOR-swizzled LDS offset for [n][K] layouts (16B chunks of 8 fp16).
__device__ __forceinline__ int sw_off(int n, int k, int K, int mask) {
    int c = k >> 3;
    return n * K + (((c ^ (n & mask)) << 3) | (k & 7));
}

// ---------------------------------------------------------------------------
__global__ void k_dm(_Float16* __restrict__ D, _Float16* __restrict__ M) {
    int k = blockIdx.x;     // 0..127
    int h = threadIdx.x;    // 0..127
    float ang = PI_F * (float)((2 * h + 1) * k) * (1.0f / 256.0f);
    float c = cosf(ang);
    D[k * 128 + h] = (_Float16)(2.0f * c);
    float wk = (k == 0) ? 0.5f : 1.0f;
    M[h * 128 + k] = (_Float16)(c * wk * (1.0f / 256.0f));
}

// WD[((k*10+s)*128+co)*32+kk] = sum_i 2cos(pi(2i+1)k/256) * w[co][ci][i][j]
//   with j = s>>1, ci = (s&1)*32 + kk
__global__ void k_wd(const float* __restrict__ w, _Float16* __restrict__ WD) {
    int bid = blockIdx.x;           // 0..1279
    int kf = bid / 10, s = bid % 10;
    int j = s >> 1, ci0 = (s & 1) << 5;
    float dv[5];
#pragma unroll
    for (int i = 0; i < 5; ++i)
        dv[i] = 2.0f * cosf(PI_F * (float)((2 * i + 1) * kf) * (1.0f / 256.0f));
    for (int e = threadIdx.x; e < 4096; e += 256) {
        int co = e >> 5, t = e & 31, ci = ci0 + t;
        const float* wp = w + (co * 64 + ci) * 25 + j;
        float acc = 0.f;
#pragma unroll
        for (int i = 0; i < 5; ++i) acc += dv[i] * wp[i * 5];
        WD[bid * 4096 + e] = (_Float16)acc;
    }
}

// ---------------------------------------------------------------------------
// Shared 128x128x128 GEMM core: lA = [m][K=128] swizzled, lB = [n][K=128] swizzled.
__device__ __forceinline__ void gemm128(const _Float16* lA, const _Float16* lB,
                                        f32x4 acc[4][4], int tid) {
    int lane = tid & 63, ln = lane & 15, q = lane >> 4;
    int wave = tid >> 6, wm = wave >> 1, wn = wave & 1;
#pragma unroll
    for (int s = 0; s < 4; ++s) {
        half8v af[4], bf[4];
#pragma unroll
        for (int mt = 0; mt < 4; ++mt) {
            int m = wm * 64 + mt * 16 + ln;
            af[mt] = *(const half8v*)(&lA[m * 128 + (((s * 4 + q) ^ (m & 15)) << 3)]);
        }
#pragma unroll
        for (int nt = 0; nt < 4; ++nt) {
            int n = wn * 64 + nt * 16 + ln;
            bf[nt] = *(const half8v*)(&lB[n * 128 + (((s * 4 + q) ^ (n & 15)) << 3)]);
        }
#pragma unroll
        for (int mt = 0; mt < 4; ++mt)
#pragma unroll
            for (int nt = 0; nt < 4; ++nt)
                acc[mt][nt] = __builtin_amdgcn_mfma_f32_16x16x32_f16(af[mt], bf[nt], acc[mt][nt], 0, 0, 0);
    }
}

// Copy a plain [128][128] fp16 matrix (rows = m, K contiguous) into swizzled LDS.
__device__ __forceinline__ void stage_copyA(const _Float16* __restrict__ g, _Float16* l, int tid) {
    const half8v* gs = (const half8v*)g;
#pragma unroll
    for (int r = 0; r < 8; ++r) {
        int gg = tid + r * 256;
        int m = gg >> 4, c = gg & 15;
        *(half8v*)(&l[m * 128 + (((c ^ (m & 15)) << 3))]) = gs[gg];
    }
}

// Transpose-stage fp16 source rows [k][128 w] (row k at src + k*row_stride) into
// swizzled LDS [n=w][K], K in {64,128}.
__device__ __forceinline__ void stage_transB(const _Float16* __restrict__ src, int row_stride,
                                             _Float16* l, int K, int mask, int nblocks, int tid) {
    for (int blk = tid; blk < nblocks; blk += 256) {
        int kb = blk >> 4, wb = blk & 15;
        int k0 = kb * 4, w0 = wb * 8;
        half8v r0 = *(const half8v*)(&src[(k0 + 0) * row_stride + w0]);
        half8v r1 = *(const half8v*)(&src[(k0 + 1) * row_stride + w0]);
        half8v r2 = *(const half8v*)(&src[(k0 + 2) * row_stride + w0]);
        half8v r3 = *(const half8v*)(&src[(k0 + 3) * row_stride + w0]);
#pragma unroll
        for (int dw = 0; dw < 8; ++dw) {
            int n = w0 + dw;
            half4v p = {r0[dw], r1[dw], r2[dw], r3[dw]};
            *(half4v*)(&l[sw_off(n, k0, K, mask)]) = p;
        }
    }
}

// ---------------------------------------------------------------------------
// Step A: xd[k][b][ci][w] = sum_h D[k][h] * x[b][ci][h][w]
__global__ __launch_bounds__(256) void k_dctH(const float* __restrict__ x,
                                              const _Float16* __restrict__ Dg,
                                              _Float16* __restrict__ xd) {
    __shared__ _Float16 lA[128 * 128];
    __shared__ _Float16 lB[128 * 128];
    int b = blockIdx.x >> 6, ci = blockIdx.x & 63;
    int tid = threadIdx.x;

    stage_copyA(Dg, lA, tid);

    const float* xs = x + (long)(b * 64 + ci) * 16384;
#pragma unroll
    for (int rep = 0; rep < 2; ++rep) {
        int blk = tid + rep * 256;
        int hb = blk >> 4, wb = blk & 15;
        int h0 = hb * 4, w0 = wb * 8;
        f32x4 f[4][2];
#pragma unroll
        for (int dh = 0; dh < 4; ++dh) {
            f[dh][0] = *(const f32x4*)(&xs[(h0 + dh) * 128 + w0]);
            f[dh][1] = *(const f32x4*)(&xs[(h0 + dh) * 128 + w0 + 4]);
        }
#pragma unroll
        for (int dw = 0; dw < 8; ++dw) {
            int n = w0 + dw;
            half4v p = {(_Float16)f[0][dw >> 2][dw & 3], (_Float16)f[1][dw >> 2][dw & 3],
                        (_Float16)f[2][dw >> 2][dw & 3], (_Float16)f[3][dw >> 2][dw & 3]};
            *(half4v*)(&lB[sw_off(n, h0, 128, 15)]) = p;
        }
    }
    __syncthreads();

    f32x4 acc[4][4] = {};
    gemm128(lA, lB, acc, tid);

    int lane = tid & 63, ln = lane & 15, q = lane >> 4;
    int wave = tid >> 6, wm = wave >> 1, wn = wave & 1;
#pragma unroll
    for (int mt = 0; mt < 4; ++mt)
#pragma unroll
        for (int nt = 0; nt < 4; ++nt)
#pragma unroll
            for (int r = 0; r < 4; ++r) {
                int kk = wm * 64 + mt * 16 + q * 4 + r;
                int wcol = wn * 64 + nt * 16 + ln;
                xd[((long)(kk * 8 + b) * 64 + ci) * 128 + wcol] = (_Float16)acc[mt][nt][r];
            }
}

// ---------------------------------------------------------------------------
// Step B: per (k,b):  y2[b][k][co][w] = sum_{s=0..9} sum_{kk} WD[k][s][co][kk] * xd[k][b][ci][(w-j)&127]
//
// b-major grid: same-k blocks land on the same XCD (bid diff = 128 == 0 mod 8)
// so the 80 KB WD k-tile is L2-resident across the 8 batches (1.25 MB/XCD).
// WD A-fragments are pure per-lane slices -> read DIRECTLY from global
// (L2-hot), no LDS, no double-buffer, no barriers in the 10-stage loop.
__global__ __launch_bounds__(256) void k_conv(const _Float16* __restrict__ xd,
                                              const _Float16* __restrict__ WD,
                                              _Float16* __restrict__ y2) {
    __shared__ _Float16 lX[128 * 64];        // [w][ci] swizzled, mask=7   (16 KB)
    int bid = blockIdx.x;
    int k = bid & 127, b = bid >> 7;
    int tid = threadIdx.x;

    // stage xd^T  (64 rows of 128) -> lX
    const _Float16* xs = xd + (long)(k * 8 + b) * 8192;
    stage_transB(xs, 128, lX, 64, 7, 256, tid);
    __syncthreads();

    int lane = tid & 63, ln = lane & 15, q = lane >> 4;
    int wave = tid >> 6, wm = wave >> 1, wn = wave & 1;
    f32x4 acc[4][4] = {};

    const _Float16* wkb = WD + (long)k * 40960;   // k * 10 * 4096

    for (int s = 0; s < 10; ++s) {
        int j = s >> 1;
        int cb = (s & 1) << 2;   // ci-chunk base within K=64
        const _Float16* wt = wkb + s * 4096;
        half8v af[4], bf[4];
#pragma unroll
        for (int mt = 0; mt < 4; ++mt) {
            int m = wm * 64 + mt * 16 + ln;
            af[mt] = *(const half8v*)(&wt[m * 32 + q * 8]);   // global, L2-hot
        }
#pragma unroll
        for (int nt = 0; nt < 4; ++nt) {
            int wcol = wn * 64 + nt * 16 + ln;
            int n = (wcol - j) & 127;
            bf[nt] = *(const half8v*)(&lX[n * 64 + (((cb + q) ^ (n & 7)) << 3)]);
        }
#pragma unroll
        for (int mt = 0; mt < 4; ++mt)
#pragma unroll
            for (int nt = 0; nt < 4; ++nt)
                acc[mt][nt] = __builtin_amdgcn_mfma_f32_16x16x32_f16(af[mt], bf[nt], acc[mt][nt], 0, 0, 0);
    }

    _Float16* yb = y2 + (long)(b * 128 + k) * 16384;
#pragma unroll
    for (int mt = 0; mt < 4; ++mt)
#pragma unroll
        for (int nt = 0; nt < 4; ++nt)
#pragma unroll
            for (int r = 0; r < 4; ++r) {
                int co = wm * 64 + mt * 16 + q * 4 + r;
                int wcol = wn * 64 + nt * 16 + ln;
                yb[co * 128 + wcol] = (_Float16)acc[mt][nt][r];
            }
}

// ---------------------------------------------------------------------------
// Step C: out[b][co][h][w] = sum_k M[h][k] * y2[b][k][co][w] + bias[co]
__global__ __launch_bounds__(256) void k_idct(const _Float16* __restrict__ y2,
                                              const _Float16* __restrict__ Mg,
                                              const float* __restrict__ bias,
                                              float* __restrict__ out) {
    __shared__ _Float16 lA[128 * 128];
    __shared__ _Float16 lB[128 * 128];
    int b = blockIdx.x >> 7, co = blockIdx.x & 127;
    int tid = threadIdx.x;

    stage_copyA(Mg, lA, tid);
    // rows k of y2 slice: base + k*16384
    const _Float16* src = y2 + (long)b * 2097152 + co * 128;
    stage_transB(src, 16384, lB, 128, 15, 512, tid);
    __syncthreads();

    f32x4 acc[4][4] = {};
    gemm128(lA, lB, acc, tid);

    float bv = bias[co];
    float* ob = out + ((long)(b * 128 + co)) * 16384;
    int lane = tid & 63, ln = lane & 15, q = lane >> 4;
    int wave = tid >> 6, wm = wave >> 1, wn = wave & 1;
#pragma unroll
    for (int mt = 0; mt < 4; ++mt)
#pragma unroll
        for (int nt = 0; nt < 4; ++nt)
#pragma unroll
            for (int r = 0; r < 4; ++r) {
                int h = wm * 64 + mt * 16 + q * 4 + r;
                int wcol = wn * 64 + nt * 16 + ln;
                ob[h * 128 + wcol] = acc[mt][nt][r] + bv;
            }
}

// ---------------------------------------------------------------------------
extern "C" void kernel_launch(void* const* d_in, const int* in_sizes, int n_in,
                              void* d_out, int out_size, void* d_ws, size_t ws_size,
                              hipStream_t stream) {
    const float* x    = (const float*)d_in[0];  // [8][64][128][128]
    const float* w    = (const float*)d_in[1];  // [128][64][5][5]
    const float* bias = (const float*)d_in[2];  // [128]
    float* out = (float*)d_out;                 // [8][128][128][128]

    char* ws = (char*)d_ws;
    _Float16* D  = (_Float16*)(ws);                                  //  32 KB
    _Float16* M  = (_Float16*)(ws + 32768);                          //  32 KB
    _Float16* WD = (_Float16*)(ws + 65536);                          //  10.0 MB
    _Float16* xd = (_Float16*)(ws + 65536 + 10485760);               //  16 MB
    _Float16* y2 = (_Float16*)(ws + 65536 + 10485760 + 16777216);    //  32 MB

    k_dm  <<<dim3(128),  dim3(128), 0, stream>>>(D, M);
    k_wd  <<<dim3(1280), dim3(256), 0, stream>>>(w, WD);
    k_dctH<<<dim3(512),  dim3(256), 0, stream>>>(x, D, xd);
    k_conv<<<dim3(1024), dim3(256), 0, stream>>>(xd, WD, y2);
    k_idct<<<dim3(1024), dim3(256), 0, stream>>>(y2, M, bias, out);
}

// Round 4
// 149.405 us; speedup vs baseline: 1.0749x; 1.0702x over previous
//
#include <hip/hip_runtime.h>

// ---------------------------------------------------------------------------
// DCT-conv:  out = IDCT_H( circconv_W( DCT_H(x), DCT_H(pad(w)) ) summed over ci ) + bias
// B=8, c_in=64, c_out=128, H=W=128, kh=kw=5.
//
// Pipeline (all fp16 storage, fp32 MFMA accumulate):
//   k_dm   : D[k][h], M[h][k] DCT matrices (fp16)
//   k_wd   : WD blocked [k][s=10][co=128][kk=32]  (LDS-staged w[co], cos table)
//   k_dctH : xd[k][b][ci][w] = D @ x[b][ci]       (512 wgs; D read from global/L1)
//   k_conv : y2[b][k][co][w] = sum_{j,ci} WD * xd shifted  (1024 wgs, b-major,
//            WD read from global/L2, barrier-free K-loop)
//   k_idct : out[b][co][h][w] = M @ y2 + bias     (1024 wgs; M from global/L1)
// ---------------------------------------------------------------------------

using half8v = __attribute__((ext_vector_type(8))) _Float16;
using half4v = __attribute__((ext_vector_type(4))) _Float16;
using f32x4  = __attribute__((ext_vector_type(4))) float;

#define PI_F 3.14159265358979323846f

// XOR-swizzled LDS offset for [n][K] layouts (16B chunks of 8 fp16).
__device__ __forceinline__ int sw_off(int n, int k, int K, int mask) {
    int c = k >> 3;
    return n * K + (((c ^ (n & mask)) << 3) | (k & 7));
}

// ---------------------------------------------------------------------------
__global__ void k_dm(_Float16* __restrict__ D, _Float16* __restrict__ M) {
    int k = blockIdx.x;     // 0..127
    int h = threadIdx.x;    // 0..127
    float ang = PI_F * (float)((2 * h + 1) * k) * (1.0f / 256.0f);
    float c = cosf(ang);
    D[k * 128 + h] = (_Float16)(2.0f * c);
    float wk = (k == 0) ? 0.5f : 1.0f;
    M[h * 128 + k] = (_Float16)(c * wk * (1.0f / 256.0f));
}

// WD[((k*10+s)*128+co)*32+kk] = sum_i 2cos(pi(2i+1)k/256) * w[co][ci][i][j]
//   with j = s>>1, ci = (s&1)*32 + kk
// One wg per (co, k-half): stage w[co] (6.4 KB) + cos table in LDS, then pure
// LDS FMAs. Replaces the old gather (80 scalar strided global loads/thread).
__global__ __launch_bounds__(256) void k_wd(const float* __restrict__ w, _Float16* __restrict__ WD) {
    __shared__ float lw[1600];      // w[co][ci][i][j]  (64*5*5)
    __shared__ float lcos[320];     // 2*cos(pi(2i+1)(k0+kl)/256), [kl][i]
    int co = blockIdx.x >> 1, k0 = (blockIdx.x & 1) << 6;
    int tid = threadIdx.x;

    for (int e = tid; e < 1600; e += 256) lw[e] = w[co * 1600 + e];
    for (int e = tid; e < 320; e += 256) {
        int kl = e / 5, i = e - kl * 5;
        lcos[e] = 2.0f * cosf(PI_F * (float)((2 * i + 1) * (k0 + kl)) * (1.0f / 256.0f));
    }
    __syncthreads();

    for (int e = tid; e < 20480; e += 256) {
        int kk = e & 31, rest = e >> 5;
        int s = rest % 10, kl = rest / 10;
        int j = s >> 1, ci = ((s & 1) << 5) + kk;
        const float* wp = &lw[ci * 25 + j];
        const float* cp = &lcos[kl * 5];
        float acc = 0.f;
#pragma unroll
        for (int i = 0; i < 5; ++i) acc += cp[i] * wp[i * 5];
        WD[(((long)(k0 + kl) * 10 + s) * 128 + co) * 32 + kk] = (_Float16)acc;
    }
}

// ---------------------------------------------------------------------------
// GEMM core with A read directly from global (L1/L2-hot 32 KB matrix, plain
// row-major [m][K=128]) and B from swizzled LDS [n][K=128].
__device__ __forceinline__ void gemm128_gA(const _Float16* __restrict__ gA,
                                           const _Float16* lB,
                                           f32x4 acc[4][4], int tid) {
    int lane = tid & 63, ln = lane & 15, q = lane >> 4;
    int wave = tid >> 6, wm = wave >> 1, wn = wave & 1;
#pragma unroll
    for (int s = 0; s < 4; ++s) {
        half8v af[4], bf[4];
#pragma unroll
        for (int mt = 0; mt < 4; ++mt) {
            int m = wm * 64 + mt * 16 + ln;
            af[mt] = *(const half8v*)(&gA[m * 128 + (s * 4 + q) * 8]);
        }
#pragma unroll
        for (int nt = 0; nt < 4; ++nt) {
            int n = wn * 64 + nt * 16 + ln;
            bf[nt] = *(const half8v*)(&lB[n * 128 + (((s * 4 + q) ^ (n & 15)) << 3)]);
        }
#pragma unroll
        for (int mt = 0; mt < 4; ++mt)
#pragma unroll
            for (int nt = 0; nt < 4; ++nt)
                acc[mt][nt] = __builtin_amdgcn_mfma_f32_16x16x32_f16(af[mt], bf[nt], acc[mt][nt], 0, 0, 0);
    }
}

// Transpose-stage fp16 source rows [k][128 w] (row k at src + k*row_stride) into
// swizzled LDS [n=w][K], K in {64,128}.
__device__ __forceinline__ void stage_transB(const _Float16* __restrict__ src, int row_stride,
                                             _Float16* l, int K, int mask, int nblocks, int tid) {
    for (int blk = tid; blk < nblocks; blk += 256) {
        int kb = blk >> 4, wb = blk & 15;
        int k0 = kb * 4, w0 = wb * 8;
        half8v r0 = *(const half8v*)(&src[(k0 + 0) * row_stride + w0]);
        half8v r1 = *(const half8v*)(&src[(k0 + 1) * row_stride + w0]);
        half8v r2 = *(const half8v*)(&src[(k0 + 2) * row_stride + w0]);
        half8v r3 = *(const half8v*)(&src[(k0 + 3) * row_stride + w0]);
#pragma unroll
        for (int dw = 0; dw < 8; ++dw) {
            int n = w0 + dw;
            half4v p = {r0[dw], r1[dw], r2[dw], r3[dw]};
            *(half4v*)(&l[sw_off(n, k0, K, mask)]) = p;
        }
    }
}

// ---------------------------------------------------------------------------
// Step A: xd[k][b][ci][w] = sum_h D[k][h] * x[b][ci][h][w]
__global__ __launch_bounds__(256) void k_dctH(const float* __restrict__ x,
                                              const _Float16* __restrict__ Dg,
                                              _Float16* __restrict__ xd) {
    __shared__ _Float16 lB[128 * 128];     // 32 KB
    int b = blockIdx.x >> 6, ci = blockIdx.x & 63;
    int tid = threadIdx.x;

    const float* xs = x + (long)(b * 64 + ci) * 16384;
#pragma unroll
    for (int rep = 0; rep < 2; ++rep) {
        int blk = tid + rep * 256;
        int hb = blk >> 4, wb = blk & 15;
        int h0 = hb * 4, w0 = wb * 8;
        f32x4 f[4][2];
#pragma unroll
        for (int dh = 0; dh < 4; ++dh) {
            f[dh][0] = *(const f32x4*)(&xs[(h0 + dh) * 128 + w0]);
            f[dh][1] = *(const f32x4*)(&xs[(h0 + dh) * 128 + w0 + 4]);
        }
#pragma unroll
        for (int dw = 0; dw < 8; ++dw) {
            int n = w0 + dw;
            half4v p = {(_Float16)f[0][dw >> 2][dw & 3], (_Float16)f[1][dw >> 2][dw & 3],
                        (_Float16)f[2][dw >> 2][dw & 3], (_Float16)f[3][dw >> 2][dw & 3]};
            *(half4v*)(&lB[sw_off(n, h0, 128, 15)]) = p;
        }
    }
    __syncthreads();

    f32x4 acc[4][4] = {};
    gemm128_gA(Dg, lB, acc, tid);

    int lane = tid & 63, ln = lane & 15, q = lane >> 4;
    int wave = tid >> 6, wm = wave >> 1, wn = wave & 1;
#pragma unroll
    for (int mt = 0; mt < 4; ++mt)
#pragma unroll
        for (int nt = 0; nt < 4; ++nt)
#pragma unroll
            for (int r = 0; r < 4; ++r) {
                int kk = wm * 64 + mt * 16 + q * 4 + r;
                int wcol = wn * 64 + nt * 16 + ln;
                xd[((long)(kk * 8 + b) * 64 + ci) * 128 + wcol] = (_Float16)acc[mt][nt][r];
            }
}

// ---------------------------------------------------------------------------
// Step B: per (k,b):  y2[b][k][co][w] = sum_{s=0..9} sum_{kk} WD[k][s][co][kk] * xd[k][b][ci][(w-j)&127]
// b-major grid keeps the 80 KB WD k-tile L2-resident across the 8 batches.
// WD A-fragments read directly from global; barrier-free 10-stage loop.
__global__ __launch_bounds__(256) void k_conv(const _Float16* __restrict__ xd,
                                              const _Float16* __restrict__ WD,
                                              _Float16* __restrict__ y2) {
    __shared__ _Float16 lX[128 * 64];        // [w][ci] swizzled, mask=7   (16 KB)
    int bid = blockIdx.x;
    int k = bid & 127, b = bid >> 7;
    int tid = threadIdx.x;

    const _Float16* xs = xd + (long)(k * 8 + b) * 8192;
    stage_transB(xs, 128, lX, 64, 7, 256, tid);
    __syncthreads();

    int lane = tid & 63, ln = lane & 15, q = lane >> 4;
    int wave = tid >> 6, wm = wave >> 1, wn = wave & 1;
    f32x4 acc[4][4] = {};

    const _Float16* wkb = WD + (long)k * 40960;   // k * 10 * 4096

    for (int s = 0; s < 10; ++s) {
        int j = s >> 1;
        int cb = (s & 1) << 2;   // ci-chunk base within K=64
        const _Float16* wt = wkb + s * 4096;
        half8v af[4], bf[4];
#pragma unroll
        for (int mt = 0; mt < 4; ++mt) {
            int m = wm * 64 + mt * 16 + ln;
            af[mt] = *(const half8v*)(&wt[m * 32 + q * 8]);   // global, L2-hot
        }
#pragma unroll
        for (int nt = 0; nt < 4; ++nt) {
            int wcol = wn * 64 + nt * 16 + ln;
            int n = (wcol - j) & 127;
            bf[nt] = *(const half8v*)(&lX[n * 64 + (((cb + q) ^ (n & 7)) << 3)]);
        }
#pragma unroll
        for (int mt = 0; mt < 4; ++mt)
#pragma unroll
            for (int nt = 0; nt < 4; ++nt)
                acc[mt][nt] = __builtin_amdgcn_mfma_f32_16x16x32_f16(af[mt], bf[nt], acc[mt][nt], 0, 0, 0);
    }

    _Float16* yb = y2 + (long)(b * 128 + k) * 16384;
#pragma unroll
    for (int mt = 0; mt < 4; ++mt)
#pragma unroll
        for (int nt = 0; nt < 4; ++nt)
#pragma unroll
            for (int r = 0; r < 4; ++r) {
                int co = wm * 64 + mt * 16 + q * 4 + r;
                int wcol = wn * 64 + nt * 16 + ln;
                yb[co * 128 + wcol] = (_Float16)acc[mt][nt][r];
            }
}

// ---------------------------------------------------------------------------
// Step C: out[b][co][h][w] = sum_k M[h][k] * y2[b][k][co][w] + bias[co]
__global__ __launch_bounds__(256) void k_idct(const _Float16* __restrict__ y2,
                                              const _Float16* __restrict__ Mg,
                                              const float* __restrict__ bias,
                                              float* __restrict__ out) {
    __shared__ _Float16 lB[128 * 128];     // 32 KB
    int b = blockIdx.x >> 7, co = blockIdx.x & 127;
    int tid = threadIdx.x;

    const _Float16* src = y2 + (long)b * 2097152 + co * 128;
    stage_transB(src, 16384, lB, 128, 15, 512, tid);
    __syncthreads();

    f32x4 acc[4][4] = {};
    gemm128_gA(Mg, lB, acc, tid);

    float bv = bias[co];
    float* ob = out + ((long)(b * 128 + co)) * 16384;
    int lane = tid & 63, ln = lane & 15, q = lane >> 4;
    int wave = tid >> 6, wm = wave >> 1, wn = wave & 1;
#pragma unroll
    for (int mt = 0; mt < 4; ++mt)
#pragma unroll
        for (int nt = 0; nt < 4; ++nt)
#pragma unroll
            for (int r = 0; r < 4; ++r) {
                int h = wm * 64 + mt * 16 + q * 4 + r;
                int wcol = wn * 64 + nt * 16 + ln;
                ob[h * 128 + wcol] = acc[mt][nt][r] + bv;
            }
}

// ---------------------------------------------------------------------------
extern "C" void kernel_launch(void* const* d_in, const int* in_sizes, int n_in,
                              void* d_out, int out_size, void* d_ws, size_t ws_size,
                              hipStream_t stream) {
    const float* x    = (const float*)d_in[0];  // [8][64][128][128]
    const float* w    = (const float*)d_in[1];  // [128][64][5][5]
    const float* bias = (const float*)d_in[2];  // [128]
    float* out = (float*)d_out;                 // [8][128][128][128]

    char* ws = (char*)d_ws;
    _Float16* D  = (_Float16*)(ws);                                  //  32 KB
    _Float16* M  = (_Float16*)(ws + 32768);                          //  32 KB
    _Float16* WD = (_Float16*)(ws + 65536);                          //  10.0 MB
    _Float16* xd = (_Float16*)(ws + 65536 + 10485760);               //  16 MB
    _Float16* y2 = (_Float16*)(ws + 65536 + 10485760 + 16777216);    //  32 MB

    k_dm  <<<dim3(128),  dim3(128), 0, stream>>>(D, M);
    k_wd  <<<dim3(256),  dim3(256), 0, stream>>>(w, WD);
    k_dctH<<<dim3(512),  dim3(256), 0, stream>>>(x, D, xd);
    k_conv<<<dim3(1024), dim3(256), 0, stream>>>(xd, WD, y2);
    k_idct<<<dim3(1024), dim3(256), 0, stream>>>(y2, M, bias, out);
}